// Round 10
// baseline (211.331 us; speedup 1.0000x reference)
//
#include <hip/hip_runtime.h>
#include <hip/hip_bf16.h>

// Problem constants
#define BB 2
#define SS 2048
#define DD 1024
#define HH 16
#define DHD 64
#define QKLD 2048  // row stride of fused QK buffer

typedef __attribute__((ext_vector_type(8))) __bf16 bf16x8;
typedef __attribute__((ext_vector_type(4))) __bf16 bf16x4;
typedef __attribute__((ext_vector_type(4))) float f32x4;
typedef __attribute__((ext_vector_type(16))) float f32x16;

__device__ __forceinline__ f32x4 mfma16(bf16x8 a, bf16x8 b, f32x4 c) {
  return __builtin_amdgcn_mfma_f32_16x16x32_bf16(a, b, c, 0, 0, 0);
}
__device__ __forceinline__ f32x16 mfma32(bf16x8 a, bf16x8 b, f32x16 c) {
  return __builtin_amdgcn_mfma_f32_32x32x16_bf16(a, b, c, 0, 0, 0);
}
__device__ __forceinline__ void gload_lds16(const void* g, void* l) {
  __builtin_amdgcn_global_load_lds((__attribute__((address_space(1))) const void*)g,
                                   (__attribute__((address_space(3))) void*)l, 16, 0, 0);
}
__device__ __forceinline__ f32x16 zero16() {
  f32x16 z;
#pragma unroll
  for (int i = 0; i < 16; ++i) z[i] = 0.f;
  return z;
}
__device__ __forceinline__ bf16x8 frag4(unsigned a, unsigned b, unsigned c, unsigned d) {
  union { unsigned u[4]; bf16x8 v; } x;
  x.u[0] = a; x.u[1] = b; x.u[2] = c; x.u[3] = d;
  return x.v;
}
// plain-C++ bf16 pair pack (src0 -> low half)
__device__ __forceinline__ unsigned pack2(float lo, float hi) {
  union { __bf16 h[2]; unsigned u; } x;
  x.h[0] = (__bf16)lo; x.h[1] = (__bf16)hi;
  return x.u;
}

// ---------------------------------------------------------------- prep kernel
__global__ __launch_bounds__(256) void prep_kernel(
    const float* __restrict__ x, __bf16* __restrict__ xb,
    const float* __restrict__ mask, __bf16* __restrict__ embf,
    const float* __restrict__ Wq, const float* __restrict__ Wk,
    const float* __restrict__ Wv, const float* __restrict__ Wo,
    __bf16* __restrict__ WTbase) {
  __shared__ __bf16 t[64][65];
  int id = blockIdx.x, tid = threadIdx.x;
  if (id < 4096) {
    int i = id * 256 + tid;
    float4 f = ((const float4*)x)[i];
    bf16x4 o;
    o[0] = (__bf16)f.x; o[1] = (__bf16)f.y; o[2] = (__bf16)f.z; o[3] = (__bf16)f.w;
    *(bf16x4*)(xb + (size_t)i * 4) = o;
    return;
  }
  if (id < 4112) {
    int j = (id - 4096) * 256 + tid;
    embf[j] = (__bf16)__expf(mask[j]);
    return;
  }
  int idx = id - 4112;
  int z = idx >> 8, rem = idx & 255;
  const float* W = (z == 0) ? Wq : (z == 1) ? Wk : (z == 2) ? Wv : Wo;
  __bf16* WT = WTbase + ((size_t)z << 20);
  int c0 = (rem & 15) * 64, r0 = (rem >> 4) * 64;
  {
    int rr = tid >> 4, cg = tid & 15;
#pragma unroll
    for (int it = 0; it < 4; ++it) {
      int r = rr + it * 16;
      float4 f = *(const float4*)(W + (size_t)(r0 + r) * DD + c0 + cg * 4);
      t[r][cg * 4 + 0] = (__bf16)f.x;
      t[r][cg * 4 + 1] = (__bf16)f.y;
      t[r][cg * 4 + 2] = (__bf16)f.z;
      t[r][cg * 4 + 3] = (__bf16)f.w;
    }
  }
  __syncthreads();
  {
    int sg = tid & 7;
#pragma unroll
    for (int it = 0; it < 2; ++it) {
      int wc = (tid >> 3) + it * 32;
      __bf16 tmp[8];
#pragma unroll
      for (int e = 0; e < 8; ++e) tmp[e] = t[sg * 8 + e][wc];
      bf16x8 o;
#pragma unroll
      for (int e = 0; e < 8; ++e) o[e] = tmp[e];
      *(bf16x8*)(WT + (size_t)(c0 + wc) * DD + r0 + sg * 8) = o;
    }
  }
}

// ---------------------------------------------------------------- GEMM body (4-wave)
template <int MODE>
__device__ __forceinline__ void gemm_body(
    char* AsB, char* BsB, int bx, int by,
    const __bf16* __restrict__ A, const __bf16* __restrict__ BT,
    float* __restrict__ Cf, __bf16* __restrict__ Cb,
    const float* __restrict__ bias, const __bf16* __restrict__ embf,
    int M, int N, int K) {
  int tid = threadIdx.x;
  int lane = tid & 63, wave = tid >> 6;
  int lr = lane & 15, lg = lane >> 4;
  int wr = wave >> 1, wc = wave & 1;
  int m0 = bx * 128, n0 = by * 128;

  int o0 = wave * 1024 + lane * 16;
  int r0i = o0 >> 6, s0i = ((o0 >> 4) & 3) ^ (r0i & 3);
  int o1 = o0 + 4096;
  int r1i = o1 >> 6, s1i = ((o1 >> 4) & 3) ^ (r1i & 3);

  const __bf16* Ag0 = A + (size_t)(m0 + r0i) * K + s0i * 8;
  const __bf16* Ag1 = A + (size_t)(m0 + r1i) * K + s1i * 8;
  const __bf16* Bg0 = BT + (size_t)(n0 + r0i) * K + s0i * 8;
  const __bf16* Bg1 = BT + (size_t)(n0 + r1i) * K + s1i * 8;
  int lb0 = wave * 1024, lb1 = wave * 1024 + 4096;

  f32x4 acc[4][4];
#pragma unroll
  for (int m = 0; m < 4; ++m)
#pragma unroll
    for (int n = 0; n < 4; ++n) acc[m][n] = (f32x4){0.f, 0.f, 0.f, 0.f};

  gload_lds16(Ag0, AsB + lb0);
  gload_lds16(Ag1, AsB + lb1);
  gload_lds16(Bg0, BsB + lb0);
  gload_lds16(Bg1, BsB + lb1);
  __syncthreads();

  int NK = K >> 5;
  for (int it = 0; it < NK; ++it) {
    int cur = it & 1;
    if (it + 1 < NK) {
      int ko = (it + 1) * 32;
      char* An = AsB + (cur ^ 1) * 8192;
      char* Bn = BsB + (cur ^ 1) * 8192;
      gload_lds16(Ag0 + ko, An + lb0);
      gload_lds16(Ag1 + ko, An + lb1);
      gload_lds16(Bg0 + ko, Bn + lb0);
      gload_lds16(Bg1 + ko, Bn + lb1);
    }
    const char* Ab = AsB + cur * 8192;
    const char* Bb = BsB + cur * 8192;
    bf16x8 af[4], bfr[4];
#pragma unroll
    for (int m = 0; m < 4; ++m) {
      int row = wr * 64 + m * 16 + lr;
      af[m] = *(const bf16x8*)(Ab + row * 64 + ((lg ^ (row & 3)) << 4));
    }
#pragma unroll
    for (int n = 0; n < 4; ++n) {
      int row = wc * 64 + n * 16 + lr;
      bfr[n] = *(const bf16x8*)(Bb + row * 64 + ((lg ^ (row & 3)) << 4));
    }
#pragma unroll
    for (int m = 0; m < 4; ++m)
#pragma unroll
      for (int n = 0; n < 4; ++n) acc[m][n] = mfma16(af[m], bfr[n], acc[m][n]);
    __syncthreads();
  }

#pragma unroll
  for (int m = 0; m < 4; ++m) {
#pragma unroll
    for (int n = 0; n < 4; ++n) {
      int cc = n0 + wc * 64 + n * 16 + lr;
      float ef = 0.f;
      if constexpr (MODE == 2) ef = (float)embf[cc];
#pragma unroll
      for (int r = 0; r < 4; ++r) {
        int rr = m0 + wr * 64 + m * 16 + 4 * lg + r;
        if constexpr (MODE == 1) {
          Cf[(size_t)rr * N + cc] = acc[m][n][r] + bias[cc];
        } else if constexpr (MODE == 0) {
          Cb[(size_t)rr * N + cc] = (__bf16)acc[m][n][r];
        } else {
          int bb2 = cc >> 11, sl = cc & (SS - 1);
          int hh = rr >> 6, dd2 = rr & 63;
          Cb[(((size_t)bb2 * HH + hh) * DHD + dd2) * SS + sl] =
              (__bf16)(acc[m][n][r] * ef);
        }
      }
    }
  }
}

// ------------- one launch: QK projection (blocks 0..511) + V' (512..767)
__global__ __launch_bounds__(256, 3) void proj_kernel(
    const __bf16* __restrict__ xb, const __bf16* __restrict__ WqT,
    const __bf16* __restrict__ WvT, __bf16* __restrict__ qkb,
    __bf16* __restrict__ vtb, const __bf16* __restrict__ embf) {
  __shared__ __bf16 As[2][128 * 32];
  __shared__ __bf16 Bs[2][128 * 32];
  int id = blockIdx.x;
  if (id < 512) {
    gemm_body<0>((char*)As, (char*)Bs, id & 31, id >> 5,
                 xb, WqT, nullptr, qkb, nullptr, nullptr, 4096, 2048, 1024);
  } else {
    int i2 = id - 512;
    gemm_body<2>((char*)As, (char*)Bs, i2 & 7, i2 >> 3,
                 WvT, xb, nullptr, vtb, nullptr, embf, 1024, 4096, 1024);
  }
}

// ------------- output projection: 512 threads, 8 waves (2x4), 64x32 wave-tiles
__global__ __launch_bounds__(512, 2) void ogemm_kernel(
    const __bf16* __restrict__ ctxb, const __bf16* __restrict__ WoT,
    float* __restrict__ out, const float* __restrict__ bo) {
  __shared__ __bf16 As[2][128 * 32];
  __shared__ __bf16 Bs[2][128 * 32];
  const int K = 1024, N = 1024;
  int tid = threadIdx.x;
  int lane = tid & 63, wave = tid >> 6;  // 0..7
  int lr = lane & 15, lg = lane >> 4;
  int wr = wave >> 2, wc = wave & 3;     // 2 x 4 wave grid
  int m0 = blockIdx.x * 128, n0 = blockIdx.y * 128;

  // staging: 512 thr x 16B = full 128x32 tile per issue; lane adds 16B to base
  int o0 = tid * 16;
  int row0 = o0 >> 6;                       // 0..127
  int s0i = ((o0 >> 4) & 3) ^ (row0 & 3);
  const __bf16* Ag = ctxb + (size_t)(m0 + row0) * K + s0i * 8;
  const __bf16* Bg = WoT + (size_t)(n0 + row0) * K + s0i * 8;
  int lb = wave * 1024;

  f32x4 acc[4][2];
#pragma unroll
  for (int m = 0; m < 4; ++m)
#pragma unroll
    for (int n = 0; n < 2; ++n) acc[m][n] = (f32x4){0.f, 0.f, 0.f, 0.f};

  gload_lds16(Ag, (char*)As[0] + lb);
  gload_lds16(Bg, (char*)Bs[0] + lb);
  __syncthreads();

  const int NK = K >> 5;
  for (int it = 0; it < NK; ++it) {
    int cur = it & 1;
    if (it + 1 < NK) {
      int ko = (it + 1) * 32;
      gload_lds16(Ag + ko, (char*)As[cur ^ 1] + lb);
      gload_lds16(Bg + ko, (char*)Bs[cur ^ 1] + lb);
    }
    const char* Ab = (const char*)As[cur];
    const char* Bb = (const char*)Bs[cur];
    bf16x8 af[4], bfr[2];
#pragma unroll
    for (int m = 0; m < 4; ++m) {
      int row = wr * 64 + m * 16 + lr;
      af[m] = *(const bf16x8*)(Ab + row * 64 + ((lg ^ (row & 3)) << 4));
    }
#pragma unroll
    for (int n = 0; n < 2; ++n) {
      int row = wc * 32 + n * 16 + lr;
      bfr[n] = *(const bf16x8*)(Bb + row * 64 + ((lg ^ (row & 3)) << 4));
    }
#pragma unroll
    for (int m = 0; m < 4; ++m)
#pragma unroll
      for (int n = 0; n < 2; ++n) acc[m][n] = mfma16(af[m], bfr[n], acc[m][n]);
    __syncthreads();
  }

#pragma unroll
  for (int m = 0; m < 4; ++m) {
#pragma unroll
    for (int n = 0; n < 2; ++n) {
      int cc = n0 + wc * 32 + n * 16 + lr;
#pragma unroll
      for (int r = 0; r < 4; ++r) {
        int rr = m0 + wr * 64 + m * 16 + 4 * lg + r;
        out[(size_t)rr * N + cc] = acc[m][n][r] + bo[cc];
      }
    }
  }
}

// ---------------------------------------------------------------- attention
// grid (S/64, H, B) = 1024 blocks, 2 waves x 32 q-rows (128 threads).
// 32x32x16 swapped QK^T (P lane-local), static softmax (em folded into V' +
// em-MFMA denominator), shfl_xor(32)+select P redistribution. More blocks/CU
// (4 vs 2) -> more independent barrier domains for pipe overlap.
__global__ __launch_bounds__(128, 2) void attn_kernel(
    const __bf16* __restrict__ QK, const __bf16* __restrict__ VT,
    const __bf16* __restrict__ embf, __bf16* __restrict__ ctxb) {
  __shared__ __bf16 Ks[2][64 * 64];
  __shared__ __bf16 Vs[2][64 * 64];

  int h = blockIdx.y, b = blockIdx.z;
  int tid = threadIdx.x;
  int wave = tid >> 6, lane = tid & 63;
  int l31 = lane & 31, hi = lane >> 5;
  int rx = l31 & 7;

  int q0 = blockIdx.x * 64 + wave * 32;
  // Q B-frags: B[k][n=q=l31], k = 8*hi+e, d = 16*kc + k
  const __bf16* qp = QK + ((size_t)(b * SS) + q0 + l31) * QKLD + h * DHD + 8 * hi;
  bf16x8 qfrag[4];
#pragma unroll
  for (int kc = 0; kc < 4; ++kc) qfrag[kc] = *(const bf16x8*)(qp + 16 * kc);

  // staging: 64x64 tile (128B rows), 128 threads -> 4 issues per tile.
  // issue j covers rows 16j+row0; linear LDS dest + inverse-swizzled source.
  int row0 = tid >> 3;                      // 0..15
  int ss0 = (tid & 7) ^ ((tid >> 3) & 7);   // source slot (uniform over j)
  int lwb = wave * 1024;                    // wave-uniform base within issue

  const __bf16* kg = QK + (size_t)(b * SS) * QKLD + DD + h * DHD;  // K at +DD
  const __bf16* vg = VT + ((size_t)(b * HH + h) * DHD) * SS;
  const __bf16* Kgj[4];
  const __bf16* Vgj[4];
#pragma unroll
  for (int j = 0; j < 4; ++j) {
    Kgj[j] = kg + (size_t)(row0 + 16 * j) * QKLD + ss0 * 8;
    Vgj[j] = vg + (size_t)(row0 + 16 * j) * SS + ss0 * 8;
  }
  const __bf16* ep = embf + b * SS + 8 * hi;

  // prologue: stage tile 0
#pragma unroll
  for (int j = 0; j < 4; ++j) {
    gload_lds16(Kgj[j], (char*)Ks[0] + j * 2048 + lwb);
    gload_lds16(Vgj[j], (char*)Vs[0] + j * 2048 + lwb);
  }

  f32x16 ctx0 = zero16(), ctx1 = zero16(), lacc = zero16();
  const float SCALE = 0.03125f;  // 1/sqrt(1024)
  __syncthreads();

  const int NT = SS / 64;
  for (int it = 0; it < NT; ++it) {
    int cur = it & 1;
    int kb = it * 64;
    if (it + 1 < NT) {
      size_t ko = (size_t)(it + 1) * 64 * QKLD;
      int vo = (it + 1) * 64;
#pragma unroll
      for (int j = 0; j < 4; ++j) {
        gload_lds16(Kgj[j] + ko, (char*)Ks[cur ^ 1] + j * 2048 + lwb);
        gload_lds16(Vgj[j] + vo, (char*)Vs[cur ^ 1] + j * 2048 + lwb);
      }
    }
    // em B-frags: element e -> em[kb + 16*q2 + 8*hi + e] (uniform in l31)
    bf16x8 emf[4];
#pragma unroll
    for (int q2 = 0; q2 < 4; ++q2) emf[q2] = *(const bf16x8*)(ep + kb + 16 * q2);

    const char* Kb = (const char*)Ks[cur];
    const char* Vb = (const char*)Vs[cur];
#pragma unroll
    for (int kc32 = 0; kc32 < 2; ++kc32) {
      // ---- QK^T (swapped): D[key][q]; A=K (row=key=kc32*32+l31), B=Q (col=q)
      f32x16 sc = zero16();
#pragma unroll
      for (int kc = 0; kc < 4; ++kc) {
        bf16x8 kf = *(const bf16x8*)(Kb + (kc32 * 32 + l31) * 128 +
                                     ((((kc << 1) + hi) ^ rx) << 4));
        sc = mfma32(kf, qfrag[kc], sc);
      }
      // ---- static softmax: p = exp(s*scale); reg i -> key (i&3)+8*(i>>2)+4*hi
      unsigned pk[8];
#pragma unroll
      for (int i2 = 0; i2 < 8; ++i2)
        pk[i2] = pack2(__expf(sc[2 * i2] * SCALE), __expf(sc[2 * i2 + 1] * SCALE));
      // ---- redistribute lo/hi halves via shfl_xor(32) + select
      unsigned sx0 = __shfl_xor(pk[0], 32, 64);
      unsigned sx1 = __shfl_xor(pk[1], 32, 64);
      unsigned sx2 = __shfl_xor(pk[2], 32, 64);
      unsigned sx3 = __shfl_xor(pk[3], 32, 64);
      unsigned sx4 = __shfl_xor(pk[4], 32, 64);
      unsigned sx5 = __shfl_xor(pk[5], 32, 64);
      unsigned sx6 = __shfl_xor(pk[6], 32, 64);
      unsigned sx7 = __shfl_xor(pk[7], 32, 64);
      unsigned w0 = hi ? sx2 : pk[0];
      unsigned w1 = hi ? sx3 : pk[1];
      unsigned w2 = hi ? pk[2] : sx0;
      unsigned w3 = hi ? pk[3] : sx1;
      unsigned w4 = hi ? sx6 : pk[4];
      unsigned w5 = hi ? sx7 : pk[5];
      unsigned w6 = hi ? pk[6] : sx4;
      unsigned w7 = hi ? pk[7] : sx5;
      bf16x8 pf0 = frag4(w0, w1, w2, w3);  // keys kc32*32 + 0..15
      bf16x8 pf1 = frag4(w4, w5, w6, w7);  // keys kc32*32 + 16..31
      // ---- denominator via em-broadcast MFMA
      lacc = mfma32(pf0, emf[kc32 * 2 + 0], lacc);
      lacc = mfma32(pf1, emf[kc32 * 2 + 1], lacc);
      // ---- PV: D[q][d] += P[q][keys] @ V'[d][keys]^T  (B col = d = l31)
      {
        bf16x8 v00 = *(const bf16x8*)(Vb + (l31)*128 + ((((kc32 << 2) + 0 + hi) ^ rx) << 4));
        ctx0 = mfma32(pf0, v00, ctx0);
        bf16x8 v01 = *(const bf16x8*)(Vb + (l31)*128 + ((((kc32 << 2) + 2 + hi) ^ rx) << 4));
        ctx0 = mfma32(pf1, v01, ctx0);
        bf16x8 v10 = *(const bf16x8*)(Vb + (32 + l31) * 128 + ((((kc32 << 2) + 0 + hi) ^ rx) << 4));
        ctx1 = mfma32(pf0, v10, ctx1);
        bf16x8 v11 = *(const bf16x8*)(Vb + (32 + l31) * 128 + ((((kc32 << 2) + 2 + hi) ^ rx) << 4));
        ctx1 = mfma32(pf1, v11, ctx1);
      }
    }
    __syncthreads();
  }
  // ---- epilogue: ctx/l; reg i -> q = (i&3)+8*(i>>2)+4*hi, d = dc*32+l31
#pragma unroll
  for (int i = 0; i < 16; ++i) {
    float inv = 1.0f / lacc[i];
    int q = (i & 3) + 8 * (i >> 2) + 4 * hi;
    __bf16* op = ctxb + ((size_t)(b * SS) + q0 + q) * DD + h * DHD + l31;
    op[0] = (__bf16)(ctx0[i] * inv);
    op[32] = (__bf16)(ctx1[i] * inv);
  }
}

// ---------------------------------------------------------------- launcher
extern "C" void kernel_launch(void* const* d_in, const int* in_sizes, int n_in,
                              void* d_out, int out_size, void* d_ws, size_t ws_size,
                              hipStream_t stream) {
  const float* x    = (const float*)d_in[0];
  const float* mask = (const float*)d_in[1];
  const float* Wq   = (const float*)d_in[2];
  const float* Wk   = (const float*)d_in[3];
  const float* Wv   = (const float*)d_in[4];
  const float* Wo   = (const float*)d_in[5];
  const float* bo   = (const float*)d_in[6];
  float* out = (float*)d_out;

  char* ws = (char*)d_ws;
  const size_t MB = 1024 * 1024;
  __bf16* xb   = (__bf16*)(ws + 0);        // 8 MB (reused as ctxb)
  __bf16* WqT  = (__bf16*)(ws + 8 * MB);   // 2 MB (WkT/WvT/WoT contiguous after)
  __bf16* WvT  = (__bf16*)(ws + 12 * MB);
  __bf16* WoT  = (__bf16*)(ws + 14 * MB);
  __bf16* qkb  = (__bf16*)(ws + 16 * MB);  // 16 MB: [4096][2048] fused Q|K
  __bf16* vtb  = (__bf16*)(ws + 32 * MB);  // 8 MB: V'[b,h,d,s] (em-folded)
  __bf16* embf = (__bf16*)(ws + 40 * MB);  // 8 KB
  __bf16* ctxb = xb;

  // 1) prep: cast x, em, 4x W transpose (one launch)
  prep_kernel<<<5136, 256, 0, stream>>>(x, xb, mask, embf, Wq, Wk, Wv, Wo, WqT);
  // 2) QK projection + transposed V' projection (one launch, 768 blocks, 3/CU)
  proj_kernel<<<768, 256, 0, stream>>>(xb, WqT, WvT, qkb, vtb, embf);
  // 3) attention: 1024 blocks x 128 threads (4 blocks/CU)
  attn_kernel<<<dim3(SS / 64, HH, BB), 128, 0, stream>>>(qkb, vtb, embf, ctxb);
  // 4) output projection: 256 blocks x 512 threads (8 waves/CU)
  ogemm_kernel<<<dim3(32, 8), 512, 0, stream>>>(ctxb, WoT, out, bo);
}